// Round 8
// baseline (1049.662 us; speedup 1.0000x reference)
//
#include <hip/hip_runtime.h>
#include <hip/hip_bf16.h>

// DIAGNOSTIC ROUND: R6 memory pattern (wave-contiguous 16 KB runs, nt
// loads/stores) + a dependent integer-LCG dilation chain per thread to push
// dur_us past the ~400 us poison fills, so this dispatch becomes the top
// rocprof row and exposes its true FETCH_SIZE / WRITE_SIZE.
// Output is identical to the reference (dilation result is dead data kept
// alive only via asm volatile, stores unchanged).

typedef int v4i __attribute__((ext_vector_type(4)));

constexpr int TPB = 256;
constexpr int VPT = 16;                // v4i per thread
constexpr int VPB = TPB * VPT;         // 4096 v4i per block (64 KB)
constexpr int DIL = 200000;            // dilation iterations (~2 VALU deps each)

__global__ __launch_bounds__(256) void q3_unpack_kernel(
    const v4i* __restrict__ in, v4i* __restrict__ out, int stride_vec) {
    const int lane = threadIdx.x & 63;
    const int w = threadIdx.x >> 6;
    const size_t wbase = (size_t)blockIdx.x * VPB + (size_t)w * (64 * VPT) + lane;

    v4i p[VPT];
#pragma unroll
    for (int j = 0; j < VPT; ++j)
        p[j] = __builtin_nontemporal_load(&in[wbase + (size_t)j * 64]);

    // --- time dilation: dependent LCG chain, result kept alive, no output effect ---
    int acc = p[0].x;
#pragma unroll 4
    for (int it = 0; it < DIL; ++it) {
        acc = acc * 1664525 + 1013904223;
    }
    asm volatile("" :: "v"(acc));
    // -------------------------------------------------------------------------------

#pragma unroll
    for (int k = 0; k < 10; ++k) {
        const int sh = 27 - 3 * k;
        const size_t ob = (size_t)k * (size_t)stride_vec + wbase;
#pragma unroll
        for (int j = 0; j < VPT; ++j) {
            v4i v = (p[j] >> sh) & 7;
            __builtin_nontemporal_store(v, &out[ob + (size_t)j * 64]);
        }
    }
}

extern "C" void kernel_launch(void* const* d_in, const int* in_sizes, int n_in,
                              void* d_out, int out_size, void* d_ws, size_t ws_size,
                              hipStream_t stream) {
    const int* packed = (const int*)d_in[0];
    int* out = (int*)d_out;

    const int n_words = in_sizes[0];     // 4096*4096 = 16,777,216
    const int nvec = n_words / 4;        // 4,194,304 v4i
    const int stride_vec = n_words / 4;  // k-block stride in v4i units

    const int blocks = nvec / VPB;       // 1024 blocks, exact fit

    q3_unpack_kernel<<<blocks, TPB, 0, stream>>>(
        (const v4i*)packed, (v4i*)out, stride_vec);
}

// Round 10
// 138.129 us; speedup vs baseline: 7.5991x; 7.5991x over previous
//
#include <hip/hip_runtime.h>
#include <hip/hip_bf16.h>

// Q3 unpack: each int32 holds 10 x 3-bit fields at shifts 27,24,...,0.
// Output block k (k=0..9) along dim 0 is ((packed >> (27-3k)) & 7), int32.
//
// Self-phased streaming: R6's wave-contiguous layout + a store-queue DRAIN
// after every k-phase. Without the drain, nt stores are fire-and-forget and
// all 10 write streams coexist at the DRAM controller (measured 4.8 TB/s
// regime); with a per-phase vmcnt(0)+barrier, each wave has ~1 stream in
// flight and the 1024 co-resident blocks (identical work) stay loosely
// time-aligned -> GPU-wide ~1-3 streams (copy/fill regime, 6.3-6.7 TB/s).
// __syncthreads() on gfx950 compiles to s_waitcnt vmcnt(0)+s_barrier, which
// is exactly the drain+align we need. Byte-minimal: input read once.

typedef int v4i __attribute__((ext_vector_type(4)));

constexpr int TPB = 256;
constexpr int VPT = 16;                // v4i per thread
constexpr int VPB = TPB * VPT;         // 4096 v4i = 64 KB per block

__global__ __launch_bounds__(256) void q3_unpack_kernel(
    const v4i* __restrict__ in, v4i* __restrict__ out, int stride_vec) {
    const int lane = threadIdx.x & 63;
    const int w = threadIdx.x >> 6;
    // wave w owns contiguous v4i range [base + w*1024, base + w*1024 + 1024)
    const size_t wbase = (size_t)blockIdx.x * VPB + (size_t)w * (64 * VPT) + lane;

    v4i p[VPT];
#pragma unroll
    for (int j = 0; j < VPT; ++j)
        p[j] = __builtin_nontemporal_load(&in[wbase + (size_t)j * 64]);

    __syncthreads();   // drain loads, align waves before the write phases

#pragma unroll
    for (int k = 0; k < 10; ++k) {
        const int sh = 27 - 3 * k;
        const size_t ob = (size_t)k * (size_t)stride_vec + wbase;
#pragma unroll
        for (int j = 0; j < VPT; ++j) {
            v4i v = (p[j] >> sh) & 7;
            __builtin_nontemporal_store(v, &out[ob + (size_t)j * 64]);
        }
        // Drain this k-stream's stores and re-align the block's waves before
        // starting stream k+1: vmcnt(0) + s_barrier.
        asm volatile("s_waitcnt vmcnt(0)" ::: "memory");
        __syncthreads();
    }
}

extern "C" void kernel_launch(void* const* d_in, const int* in_sizes, int n_in,
                              void* d_out, int out_size, void* d_ws, size_t ws_size,
                              hipStream_t stream) {
    const int* packed = (const int*)d_in[0];
    int* out = (int*)d_out;

    const int n_words = in_sizes[0];     // 4096*4096 = 16,777,216
    const int nvec = n_words / 4;        // 4,194,304 v4i
    const int stride_vec = n_words / 4;  // k-block stride in v4i units

    const int blocks = nvec / VPB;       // 1024 blocks, exact fit (4/CU)

    q3_unpack_kernel<<<blocks, TPB, 0, stream>>>(
        (const v4i*)packed, (v4i*)out, stride_vec);
}